// Round 4
// baseline (186.698 us; speedup 1.0000x reference)
//
#include <hip/hip_runtime.h>
#include <cstdint>
#include <cstddef>

typedef __attribute__((ext_vector_type(8))) short short8;
typedef __attribute__((ext_vector_type(4))) float f32x4;

#define NROW 4096
#define NCOL 128
#define SPLIT 8

__device__ __forceinline__ unsigned short f2b(float f) {
  unsigned int u = __builtin_bit_cast(unsigned int, f);
  u += 0x7fffu + ((u >> 16) & 1u);   // round-to-nearest-even to bf16
  return (unsigned short)(u >> 16);
}

// ---------------- prep: Theta f32 [4096][4096] -> Thb (row-major bf16) + Ttb (transposed bf16)
__global__ __launch_bounds__(256) void prep_theta(unsigned short* __restrict__ Thb,
    unsigned short* __restrict__ Ttb, const float* __restrict__ Th)
{
  __shared__ float sh[64][65];
  const int r0 = blockIdx.x * 64, c0 = blockIdx.y * 64;
  const int t = threadIdx.x;
  const int c4 = (t & 15) * 4;
#pragma unroll
  for (int it = 0; it < 4; ++it) {
    int r = (t >> 4) + it * 16;
    float4 v = *(const float4*)(Th + (size_t)(r0 + r) * 4096 + c0 + c4);
    ushort4 o; o.x = f2b(v.x); o.y = f2b(v.y); o.z = f2b(v.z); o.w = f2b(v.w);
    *(ushort4*)(Thb + (size_t)(r0 + r) * 4096 + c0 + c4) = o;
    sh[r][c4 + 0] = v.x; sh[r][c4 + 1] = v.y; sh[r][c4 + 2] = v.z; sh[r][c4 + 3] = v.w;
  }
  __syncthreads();
  const int r4 = (t & 15) * 4;
#pragma unroll
  for (int it = 0; it < 4; ++it) {
    int c = (t >> 4) + it * 16;
    ushort4 o;
    o.x = f2b(sh[r4 + 0][c]); o.y = f2b(sh[r4 + 1][c]);
    o.z = f2b(sh[r4 + 2][c]); o.w = f2b(sh[r4 + 3][c]);
    *(ushort4*)(Ttb + (size_t)(c0 + c) * 4096 + r0 + r4) = o;
  }
}

// ---------------- elementwise f32 -> bf16
__global__ __launch_bounds__(256) void cvt_bf16(unsigned short* __restrict__ dst,
                                                const float* __restrict__ src)
{
  size_t i = ((size_t)blockIdx.x * 256 + threadIdx.x) * 4;
  float4 v = *(const float4*)(src + i);
  ushort4 o; o.x = f2b(v.x); o.y = f2b(v.y); o.z = f2b(v.z); o.w = f2b(v.w);
  *(ushort4*)(dst + i) = o;
}

// ---------------- f32 [R][128] -> bf16 [128][R] (transpose + convert) — for W1/W2 only
__global__ __launch_bounds__(256) void transpose_cvt(unsigned short* __restrict__ outT,
    const float* __restrict__ in, int R)
{
  __shared__ float sh[32][33];
  const int r0 = blockIdx.x * 32, c0 = blockIdx.y * 32;
  const int t = threadIdx.x;
  {
    int r = t >> 3, c4 = (t & 7) * 4;
    float4 v = *(const float4*)(in + (size_t)(r0 + r) * 128 + c0 + c4);
    sh[r][c4 + 0] = v.x; sh[r][c4 + 1] = v.y; sh[r][c4 + 2] = v.z; sh[r][c4 + 3] = v.w;
  }
  __syncthreads();
  {
    int c = t >> 3, j4 = (t & 7) * 4;
    ushort4 o;
    o.x = f2b(sh[j4 + 0][c]); o.y = f2b(sh[j4 + 1][c]);
    o.z = f2b(sh[j4 + 2][c]); o.w = f2b(sh[j4 + 3][c]);
    *(ushort4*)(outT + (size_t)(c0 + c) * R + r0 + j4) = o;
  }
}

// ================= old 64x64 reg-staged core: kept for the two small GEMMs =================
__device__ __forceinline__ void gemm_core(
    f32x4& acc00, f32x4& acc01, f32x4& acc10, f32x4& acc11,
    const unsigned short* __restrict__ A, const unsigned short* __restrict__ Bt,
    int K, int kbeg, int kend, int m0, int n0,
    unsigned short* As, unsigned short* Bs)
{
  const int tid = threadIdx.x;
  const int lane = tid & 63;
  const int w = tid >> 6;
  const int wr = w >> 1, wc = w & 1;

  const int r_st = tid >> 3;
  const int cc = tid & 7;
  const unsigned short* Ap0 = A + (size_t)(m0 + r_st) * K + cc * 8;
  const unsigned short* Ap1 = A + (size_t)(m0 + r_st + 32) * K + cc * 8;
  const unsigned short* Bp0 = Bt + (size_t)(n0 + r_st) * K + cc * 8;
  const unsigned short* Bp1 = Bt + (size_t)(n0 + r_st + 32) * K + cc * 8;
  const int wb0 = r_st * 128 + ((cc * 16) ^ ((r_st & 7) << 4));
  const int wb1 = wb0 + 32 * 128;

  char* AsB = (char*)As;
  char* BsB = (char*)Bs;
  const int krow = lane & 15, kgrp = lane >> 4;
  const int r0L = wr * 32 + krow;
  const int c0L = wc * 32 + krow;
  const int sw_r = (r0L & 7) << 4;
  const int sw_c = (c0L & 7) << 4;

  for (int k0 = kbeg; k0 < kend; k0 += 64) {
    short8 a0 = *(const short8*)(const void*)(Ap0 + k0);
    short8 a1 = *(const short8*)(const void*)(Ap1 + k0);
    short8 b0 = *(const short8*)(const void*)(Bp0 + k0);
    short8 b1 = *(const short8*)(const void*)(Bp1 + k0);
    __syncthreads();
    *(short8*)(AsB + wb0) = a0;
    *(short8*)(AsB + wb1) = a1;
    *(short8*)(BsB + wb0) = b0;
    *(short8*)(BsB + wb1) = b1;
    __syncthreads();
#pragma unroll
    for (int kk = 0; kk < 64; kk += 32) {
      const int kb = (kk + 8 * kgrp) * 2;
      short8 af0 = *(const short8*)(AsB + r0L * 128 + (kb ^ sw_r));
      short8 af1 = *(const short8*)(AsB + (r0L + 16) * 128 + (kb ^ sw_r));
      short8 bf0 = *(const short8*)(BsB + c0L * 128 + (kb ^ sw_c));
      short8 bf1 = *(const short8*)(BsB + (c0L + 16) * 128 + (kb ^ sw_c));
      acc00 = __builtin_amdgcn_mfma_f32_16x16x32_bf16(af0, bf0, acc00, 0, 0, 0);
      acc01 = __builtin_amdgcn_mfma_f32_16x16x32_bf16(af0, bf1, acc01, 0, 0, 0);
      acc10 = __builtin_amdgcn_mfma_f32_16x16x32_bf16(af1, bf0, acc10, 0, 0, 0);
      acc11 = __builtin_amdgcn_mfma_f32_16x16x32_bf16(af1, bf1, acc11, 0, 0, 0);
    }
  }
}

// small GEMM (fw = x@W): whole K, writes C f32 row-major + Ct bf16 [128, NROW]
__global__ __launch_bounds__(256) void gemm_small(float* __restrict__ C,
    unsigned short* __restrict__ Ct,
    const unsigned short* __restrict__ A, const unsigned short* __restrict__ Bt, int K)
{
  __shared__ __align__(16) unsigned short As[64 * 64];
  __shared__ __align__(16) unsigned short Bs[64 * 64];
  const int m0 = blockIdx.x * 64, n0 = blockIdx.y * 64;
  f32x4 acc00 = {}, acc01 = {}, acc10 = {}, acc11 = {};
  gemm_core(acc00, acc01, acc10, acc11, A, Bt, K, 0, K, m0, n0, As, Bs);

  const int lane = threadIdx.x & 63;
  const int w = threadIdx.x >> 6;
  const int orow = m0 + (w >> 1) * 32 + (lane >> 4) * 4;
  const int ocol = n0 + (w & 1) * 32 + (lane & 15);
#pragma unroll
  for (int reg = 0; reg < 4; ++reg) {
    C[(size_t)(orow + reg) * 128 + ocol]           = acc00[reg];
    C[(size_t)(orow + reg) * 128 + ocol + 16]      = acc01[reg];
    C[(size_t)(orow + 16 + reg) * 128 + ocol]      = acc10[reg];
    C[(size_t)(orow + 16 + reg) * 128 + ocol + 16] = acc11[reg];
  }
  ushort4 o;
  o.x = f2b(acc00[0]); o.y = f2b(acc00[1]); o.z = f2b(acc00[2]); o.w = f2b(acc00[3]);
  *(ushort4*)(Ct + (size_t)ocol * NROW + orow) = o;
  o.x = f2b(acc10[0]); o.y = f2b(acc10[1]); o.z = f2b(acc10[2]); o.w = f2b(acc10[3]);
  *(ushort4*)(Ct + (size_t)ocol * NROW + orow + 16) = o;
  o.x = f2b(acc01[0]); o.y = f2b(acc01[1]); o.z = f2b(acc01[2]); o.w = f2b(acc01[3]);
  *(ushort4*)(Ct + (size_t)(ocol + 16) * NROW + orow) = o;
  o.x = f2b(acc11[0]); o.y = f2b(acc11[1]); o.z = f2b(acc11[2]); o.w = f2b(acc11[3]);
  *(ushort4*)(Ct + (size_t)(ocol + 16) * NROW + orow + 16) = o;
}

// ================= m97-style split-K GEMM: BM=64 x BN=128 (full width), BK=64 =================
// A[M,K] bf16 rm, Bt[128,K] bf16. grid (64, 1, SPLIT). global_load_lds dwordx4 staging
// with pre-swizzled global source (mask ((r&7)<<4)); linear LDS dest; swizzled ds_read_b128.
// 4 waves in 2x2: wave covers 32 rows x 64 cols = 2x4 fragments of 16x16, K-sub 32 x2.
__global__ __launch_bounds__(256) void gemm_sk(float* __restrict__ P,
    const unsigned short* __restrict__ A, const unsigned short* __restrict__ Bt,
    int K, int KS)
{
  __shared__ __align__(16) unsigned short As[64 * 64];    // 8 KB, swizzled
  __shared__ __align__(16) unsigned short Bs[128 * 64];   // 16 KB, swizzled
  const int tid = threadIdx.x;
  const int lane = tid & 63;
  const int w = tid >> 6;
  const int wr = w >> 1, wc = w & 1;
  const int m0 = blockIdx.x * 64;
  const int s = blockIdx.z;
  const int kbeg = s * KS, kend = kbeg + KS;

  // ---- staging addresses: each instr moves 8 rows x 128B; lane -> (row lane>>3, byte (lane&7)*16)
  // source byte within row is XOR-preswizzled so linear LDS write == swizzled layout
  const int lrow = lane >> 3;                       // 0..7
  const int osw = (((lane & 7) ^ lrow) << 4);       // pre-swizzled byte offset in 128B row
  const unsigned char* Ab = (const unsigned char*)A;
  const unsigned char* Bb = (const unsigned char*)Bt;
  size_t a_src[2], b_src[4];
#pragma unroll
  for (int i = 0; i < 2; ++i)                       // A rows: w*16 + i*8 + lrow  (0..63)
    a_src[i] = (size_t)(m0 + w * 16 + i * 8 + lrow) * ((size_t)K * 2) + osw;
#pragma unroll
  for (int j = 0; j < 4; ++j)                       // B rows: w*32 + j*8 + lrow  (0..127)
    b_src[j] = (size_t)(w * 32 + j * 8 + lrow) * ((size_t)K * 2) + osw;

  char* AsB = (char*)As;
  char* BsB = (char*)Bs;

  f32x4 acc[2][4] = {};

  const int krow = lane & 15, kgrp = lane >> 4;
  const int rA = wr * 32 + krow;                    // + mf*16 ; (r&7) == lane&7
  const int rB = wc * 64 + krow;                    // + nf*16 ; (r&7) == lane&7
  const int swz = (lane & 7) << 4;
  const int kb_base = kgrp * 16;                    // byte offset of lane's 8 k-elems

  for (int k0 = kbeg; k0 < kend; k0 += 64) {
    __syncthreads();                                // previous compute done
#pragma unroll
    for (int i = 0; i < 2; ++i)
      __builtin_amdgcn_global_load_lds(
          (const __attribute__((address_space(1))) void*)(Ab + a_src[i] + (size_t)k0 * 2),
          (__attribute__((address_space(3))) void*)(AsB + (w * 2 + i) * 1024), 16, 0, 0);
#pragma unroll
    for (int j = 0; j < 4; ++j)
      __builtin_amdgcn_global_load_lds(
          (const __attribute__((address_space(1))) void*)(Bb + b_src[j] + (size_t)k0 * 2),
          (__attribute__((address_space(3))) void*)(BsB + (w * 4 + j) * 1024), 16, 0, 0);
    __syncthreads();                                // drains vmcnt before use
#pragma unroll
    for (int ks = 0; ks < 2; ++ks) {
      const int kb = ks * 64 + kb_base;
      short8 af0 = *(const short8*)(AsB + (rA) * 128 + (kb ^ swz));
      short8 af1 = *(const short8*)(AsB + (rA + 16) * 128 + (kb ^ swz));
      short8 bf0 = *(const short8*)(BsB + (rB) * 128 + (kb ^ swz));
      short8 bf1 = *(const short8*)(BsB + (rB + 16) * 128 + (kb ^ swz));
      short8 bf2 = *(const short8*)(BsB + (rB + 32) * 128 + (kb ^ swz));
      short8 bf3 = *(const short8*)(BsB + (rB + 48) * 128 + (kb ^ swz));
      acc[0][0] = __builtin_amdgcn_mfma_f32_16x16x32_bf16(af0, bf0, acc[0][0], 0, 0, 0);
      acc[0][1] = __builtin_amdgcn_mfma_f32_16x16x32_bf16(af0, bf1, acc[0][1], 0, 0, 0);
      acc[0][2] = __builtin_amdgcn_mfma_f32_16x16x32_bf16(af0, bf2, acc[0][2], 0, 0, 0);
      acc[0][3] = __builtin_amdgcn_mfma_f32_16x16x32_bf16(af0, bf3, acc[0][3], 0, 0, 0);
      acc[1][0] = __builtin_amdgcn_mfma_f32_16x16x32_bf16(af1, bf0, acc[1][0], 0, 0, 0);
      acc[1][1] = __builtin_amdgcn_mfma_f32_16x16x32_bf16(af1, bf1, acc[1][1], 0, 0, 0);
      acc[1][2] = __builtin_amdgcn_mfma_f32_16x16x32_bf16(af1, bf2, acc[1][2], 0, 0, 0);
      acc[1][3] = __builtin_amdgcn_mfma_f32_16x16x32_bf16(af1, bf3, acc[1][3], 0, 0, 0);
    }
  }

  float* C = P + (size_t)s * NROW * NCOL;
  const int orow = m0 + wr * 32 + kgrp * 4;         // C/D layout (m89): col=lane&15, row=(lane>>4)*4+reg
  const int ocol = wc * 64 + krow;
#pragma unroll
  for (int mf = 0; mf < 2; ++mf)
#pragma unroll
    for (int nf = 0; nf < 4; ++nf)
#pragma unroll
      for (int reg = 0; reg < 4; ++reg)
        C[(size_t)(orow + mf * 16 + reg) * 128 + ocol + nf * 16] = acc[mf][nf][reg];
}

// ================= reduce: sum SPLIT partials, optional combine, write f32 + bf16^T
// MODE 0: out = sum            MODE 1: out = d .* (p3*x1 + p4*x2 + p5*sum)
template<int MODE>
__global__ __launch_bounds__(256) void reduce_tr(float* __restrict__ outF,
    unsigned short* __restrict__ outT, const float* __restrict__ P,
    const float* __restrict__ x1, const float* __restrict__ x2,
    const float* __restrict__ dv, const float* __restrict__ par)
{
  __shared__ float sh[32][33];
  const int r0 = blockIdx.x * 32, c0 = blockIdx.y * 32;
  const int t = threadIdx.x;
  const int r = t >> 3, c4 = (t & 7) * 4;
  const size_t base = (size_t)(r0 + r) * 128 + c0 + c4;

  float4 acc = *(const float4*)(P + base);
#pragma unroll
  for (int s = 1; s < SPLIT; ++s) {
    float4 v = *(const float4*)(P + (size_t)s * NROW * NCOL + base);
    acc.x += v.x; acc.y += v.y; acc.z += v.z; acc.w += v.w;
  }
  if (MODE == 1) {
    float d_ = dv[r0 + r];
    float p3 = par[3], p4 = par[4], p5 = par[5];
    float4 a = *(const float4*)(x1 + base);
    float4 b = *(const float4*)(x2 + base);
    acc.x = d_ * (p3 * a.x + p4 * b.x + p5 * acc.x);
    acc.y = d_ * (p3 * a.y + p4 * b.y + p5 * acc.y);
    acc.z = d_ * (p3 * a.z + p4 * b.z + p5 * acc.z);
    acc.w = d_ * (p3 * a.w + p4 * b.w + p5 * acc.w);
  }
  *(float4*)(outF + base) = acc;
  sh[r][c4 + 0] = acc.x; sh[r][c4 + 1] = acc.y; sh[r][c4 + 2] = acc.z; sh[r][c4 + 3] = acc.w;
  __syncthreads();
  const int c = t >> 3, j4 = (t & 7) * 4;
  ushort4 o;
  o.x = f2b(sh[j4 + 0][c]); o.y = f2b(sh[j4 + 1][c]);
  o.z = f2b(sh[j4 + 2][c]); o.w = f2b(sh[j4 + 3][c]);
  *(ushort4*)(outT + (size_t)(c0 + c) * NROW + r0 + j4) = o;
}

// h1 = relu(p0*y + p1*q1 + p2*sum(P)) -> bf16 row-major
__global__ __launch_bounds__(256) void reduce_h1(unsigned short* __restrict__ ho,
    const float* __restrict__ P, const float* __restrict__ y,
    const float* __restrict__ q1, const float* __restrict__ par)
{
  size_t i = ((size_t)blockIdx.x * 256 + threadIdx.x) * 4;
  float4 acc = *(const float4*)(P + i);
#pragma unroll
  for (int s = 1; s < SPLIT; ++s) {
    float4 v = *(const float4*)(P + (size_t)s * NROW * NCOL + i);
    acc.x += v.x; acc.y += v.y; acc.z += v.z; acc.w += v.w;
  }
  float p0 = par[0], p1 = par[1], p2 = par[2];
  float4 a = *(const float4*)(y + i), b = *(const float4*)(q1 + i);
  ushort4 o;
  o.x = f2b(fmaxf(p0 * a.x + p1 * b.x + p2 * acc.x, 0.f));
  o.y = f2b(fmaxf(p0 * a.y + p1 * b.y + p2 * acc.y, 0.f));
  o.z = f2b(fmaxf(p0 * a.z + p1 * b.z + p2 * acc.z, 0.f));
  o.w = f2b(fmaxf(p0 * a.w + p1 * b.w + p2 * acc.w, 0.f));
  *(ushort4*)(ho + i) = o;
}

// out = (ps0+ps1) * log_softmax(p0*y + p1*q1 + p2*sum(P), rows of 128) -> f32
__global__ __launch_bounds__(256) void final_sum(float* __restrict__ out,
    const float* __restrict__ P, const float* __restrict__ y,
    const float* __restrict__ q1, const float* __restrict__ par,
    const float* __restrict__ ps)
{
  int row = blockIdx.x * 4 + (threadIdx.x >> 6);
  int lane = threadIdx.x & 63;
  size_t i0 = (size_t)row * 128 + lane;
  size_t i1 = i0 + 64;
  float s0 = 0.f, s1 = 0.f;
#pragma unroll
  for (int s = 0; s < SPLIT; ++s) {
    s0 += P[(size_t)s * NROW * NCOL + i0];
    s1 += P[(size_t)s * NROW * NCOL + i1];
  }
  float p0 = par[0], p1 = par[1], p2 = par[2];
  float a0 = p0 * y[i0] + p1 * q1[i0] + p2 * s0;
  float a1 = p0 * y[i1] + p1 * q1[i1] + p2 * s1;
  float m = fmaxf(a0, a1);
#pragma unroll
  for (int off = 32; off; off >>= 1) m = fmaxf(m, __shfl_xor(m, off));
  float s = expf(a0 - m) + expf(a1 - m);
#pragma unroll
  for (int off = 32; off; off >>= 1) s += __shfl_xor(s, off);
  float ls = m + logf(s);
  float c = ps[0] + ps[1];
  out[i0] = c * (a0 - ls);
  out[i1] = c * (a1 - ls);
}

extern "C" void kernel_launch(void* const* d_in, const int* in_sizes, int n_in,
                              void* d_out, int out_size, void* d_ws, size_t ws_size,
                              hipStream_t stream) {
  (void)in_sizes; (void)n_in; (void)out_size; (void)ws_size;
  const float* features = (const float*)d_in[0];
  const float* Theta    = (const float*)d_in[1];
  const float* W1       = (const float*)d_in[2];
  const float* d1       = (const float*)d_in[3];
  const float* par1     = (const float*)d_in[4];
  const float* W2       = (const float*)d_in[5];
  const float* d2       = (const float*)d_in[6];
  const float* par2     = (const float*)d_in[7];
  const float* psnap    = (const float*)d_in[8];
  float* out            = (float*)d_out;

  char* w = (char*)d_ws;
  unsigned short* Thb  = (unsigned short*)w;  w += (size_t)4096 * 4096 * 2;
  unsigned short* Ttb  = (unsigned short*)w;  w += (size_t)4096 * 4096 * 2;
  unsigned short* fb   = (unsigned short*)w;  w += (size_t)4096 * 512 * 2;
  unsigned short* W1bt = (unsigned short*)w;  w += (size_t)128 * 512 * 2;
  unsigned short* W2bt = (unsigned short*)w;  w += (size_t)128 * 128 * 2;
  unsigned short* fwbt = (unsigned short*)w;  w += (size_t)128 * 4096 * 2;
  unsigned short* t1bt = (unsigned short*)w;  w += (size_t)128 * 4096 * 2;
  unsigned short* ybt  = (unsigned short*)w;  w += (size_t)128 * 4096 * 2;
  unsigned short* p1bt = (unsigned short*)w;  w += (size_t)128 * 4096 * 2;
  unsigned short* h1b  = (unsigned short*)w;  w += (size_t)4096 * 128 * 2;
  float* fwf = (float*)w;                     w += (size_t)4096 * 128 * 4;
  float* t1f = (float*)w;                     w += (size_t)4096 * 128 * 4;
  float* yf  = (float*)w;                     w += (size_t)4096 * 128 * 4;
  float* p1f = (float*)w;                     w += (size_t)4096 * 128 * 4;
  float* Pp  = (float*)w;                     w += (size_t)SPLIT * 4096 * 128 * 4;

  // prep
  prep_theta<<<dim3(64, 64), 256, 0, stream>>>(Thb, Ttb, Theta);
  cvt_bf16<<<2048, 256, 0, stream>>>(fb, features);
  transpose_cvt<<<dim3(16, 4), 256, 0, stream>>>(W1bt, W1, 512);
  transpose_cvt<<<dim3(4, 4), 256, 0, stream>>>(W2bt, W2, 128);

  const dim3 gg(64, 2);            // small GEMM grid
  const dim3 gk(64, 1, SPLIT);     // split-K GEMM grid (512 blocks, full-width tiles)
  const dim3 rg(128, 4);           // reduce_tr grid

  // ---- layer 1
  gemm_small<<<gg, 256, 0, stream>>>(fwf, fwbt, fb, W1bt, 512);
  gemm_sk<<<gk, 256, 0, stream>>>(Pp, Ttb, fwbt, 4096, 512);
  reduce_tr<0><<<rg, 256, 0, stream>>>(t1f, t1bt, Pp, nullptr, nullptr, nullptr, nullptr);
  gemm_sk<<<gk, 256, 0, stream>>>(Pp, Ttb, t1bt, 4096, 512);
  reduce_tr<1><<<rg, 256, 0, stream>>>(yf, ybt, Pp, fwf, t1f, d1, par1);
  gemm_sk<<<gk, 256, 0, stream>>>(Pp, Thb, ybt, 4096, 512);
  reduce_tr<0><<<rg, 256, 0, stream>>>(p1f, p1bt, Pp, nullptr, nullptr, nullptr, nullptr);
  gemm_sk<<<gk, 256, 0, stream>>>(Pp, Thb, p1bt, 4096, 512);
  reduce_h1<<<512, 256, 0, stream>>>(h1b, Pp, yf, p1f, par1);

  // ---- layer 2
  gemm_small<<<gg, 256, 0, stream>>>(fwf, fwbt, h1b, W2bt, 128);
  gemm_sk<<<gk, 256, 0, stream>>>(Pp, Ttb, fwbt, 4096, 512);
  reduce_tr<0><<<rg, 256, 0, stream>>>(t1f, t1bt, Pp, nullptr, nullptr, nullptr, nullptr);
  gemm_sk<<<gk, 256, 0, stream>>>(Pp, Ttb, t1bt, 4096, 512);
  reduce_tr<1><<<rg, 256, 0, stream>>>(yf, ybt, Pp, fwf, t1f, d2, par2);
  gemm_sk<<<gk, 256, 0, stream>>>(Pp, Thb, ybt, 4096, 512);
  reduce_tr<0><<<rg, 256, 0, stream>>>(p1f, p1bt, Pp, nullptr, nullptr, nullptr, nullptr);
  gemm_sk<<<gk, 256, 0, stream>>>(Pp, Thb, p1bt, 4096, 512);
  final_sum<<<1024, 256, 0, stream>>>(out, Pp, yf, p1f, par2, psnap);
}

// Round 5
// 176.254 us; speedup vs baseline: 1.0593x; 1.0593x over previous
//
#include <hip/hip_runtime.h>
#include <cstdint>
#include <cstddef>

typedef __attribute__((ext_vector_type(8))) short short8;
typedef __attribute__((ext_vector_type(4))) float f32x4;

#define NROW 4096
#define NCOL 128
#define SPLIT 8
#define NM ((size_t)NROW * NCOL)

__device__ __forceinline__ unsigned short f2b(float f) {
  unsigned int u = __builtin_bit_cast(unsigned int, f);
  u += 0x7fffu + ((u >> 16) & 1u);   // round-to-nearest-even to bf16
  return (unsigned short)(u >> 16);
}
__device__ __forceinline__ float b2f(unsigned short b) {
  unsigned int u = ((unsigned int)b) << 16;
  return __builtin_bit_cast(float, u);
}

// ---------------- prep: Theta f32 [4096][4096] -> Thb (row-major bf16) + Ttb (transposed bf16)
__global__ __launch_bounds__(256) void prep_theta(unsigned short* __restrict__ Thb,
    unsigned short* __restrict__ Ttb, const float* __restrict__ Th)
{
  __shared__ float sh[64][65];
  const int r0 = blockIdx.x * 64, c0 = blockIdx.y * 64;
  const int t = threadIdx.x;
  const int c4 = (t & 15) * 4;
#pragma unroll
  for (int it = 0; it < 4; ++it) {
    int r = (t >> 4) + it * 16;
    float4 v = *(const float4*)(Th + (size_t)(r0 + r) * 4096 + c0 + c4);
    ushort4 o; o.x = f2b(v.x); o.y = f2b(v.y); o.z = f2b(v.z); o.w = f2b(v.w);
    *(ushort4*)(Thb + (size_t)(r0 + r) * 4096 + c0 + c4) = o;
    sh[r][c4 + 0] = v.x; sh[r][c4 + 1] = v.y; sh[r][c4 + 2] = v.z; sh[r][c4 + 3] = v.w;
  }
  __syncthreads();
  const int r4 = (t & 15) * 4;
#pragma unroll
  for (int it = 0; it < 4; ++it) {
    int c = (t >> 4) + it * 16;
    ushort4 o;
    o.x = f2b(sh[r4 + 0][c]); o.y = f2b(sh[r4 + 1][c]);
    o.z = f2b(sh[r4 + 2][c]); o.w = f2b(sh[r4 + 3][c]);
    *(ushort4*)(Ttb + (size_t)(c0 + c) * 4096 + r0 + r4) = o;
  }
}

// ---------------- elementwise f32 -> bf16
__global__ __launch_bounds__(256) void cvt_bf16(unsigned short* __restrict__ dst,
                                                const float* __restrict__ src)
{
  size_t i = ((size_t)blockIdx.x * 256 + threadIdx.x) * 4;
  float4 v = *(const float4*)(src + i);
  ushort4 o; o.x = f2b(v.x); o.y = f2b(v.y); o.z = f2b(v.z); o.w = f2b(v.w);
  *(ushort4*)(dst + i) = o;
}

// ---------------- f32 [R][128] -> bf16 [128][R] (transpose + convert) — for W1/W2 only
__global__ __launch_bounds__(256) void transpose_cvt(unsigned short* __restrict__ outT,
    const float* __restrict__ in, int R)
{
  __shared__ float sh[32][33];
  const int r0 = blockIdx.x * 32, c0 = blockIdx.y * 32;
  const int t = threadIdx.x;
  {
    int r = t >> 3, c4 = (t & 7) * 4;
    float4 v = *(const float4*)(in + (size_t)(r0 + r) * 128 + c0 + c4);
    sh[r][c4 + 0] = v.x; sh[r][c4 + 1] = v.y; sh[r][c4 + 2] = v.z; sh[r][c4 + 3] = v.w;
  }
  __syncthreads();
  {
    int c = t >> 3, j4 = (t & 7) * 4;
    ushort4 o;
    o.x = f2b(sh[j4 + 0][c]); o.y = f2b(sh[j4 + 1][c]);
    o.z = f2b(sh[j4 + 2][c]); o.w = f2b(sh[j4 + 3][c]);
    *(ushort4*)(outT + (size_t)(c0 + c) * R + r0 + j4) = o;
  }
}

// ================= old 64x64 reg-staged core: kept for the two small GEMMs =================
__device__ __forceinline__ void gemm_core(
    f32x4& acc00, f32x4& acc01, f32x4& acc10, f32x4& acc11,
    const unsigned short* __restrict__ A, const unsigned short* __restrict__ Bt,
    int K, int kbeg, int kend, int m0, int n0,
    unsigned short* As, unsigned short* Bs)
{
  const int tid = threadIdx.x;
  const int lane = tid & 63;
  const int w = tid >> 6;
  const int wr = w >> 1, wc = w & 1;

  const int r_st = tid >> 3;
  const int cc = tid & 7;
  const unsigned short* Ap0 = A + (size_t)(m0 + r_st) * K + cc * 8;
  const unsigned short* Ap1 = A + (size_t)(m0 + r_st + 32) * K + cc * 8;
  const unsigned short* Bp0 = Bt + (size_t)(n0 + r_st) * K + cc * 8;
  const unsigned short* Bp1 = Bt + (size_t)(n0 + r_st + 32) * K + cc * 8;
  const int wb0 = r_st * 128 + ((cc * 16) ^ ((r_st & 7) << 4));
  const int wb1 = wb0 + 32 * 128;

  char* AsB = (char*)As;
  char* BsB = (char*)Bs;
  const int krow = lane & 15, kgrp = lane >> 4;
  const int r0L = wr * 32 + krow;
  const int c0L = wc * 32 + krow;
  const int sw_r = (r0L & 7) << 4;
  const int sw_c = (c0L & 7) << 4;

  for (int k0 = kbeg; k0 < kend; k0 += 64) {
    short8 a0 = *(const short8*)(const void*)(Ap0 + k0);
    short8 a1 = *(const short8*)(const void*)(Ap1 + k0);
    short8 b0 = *(const short8*)(const void*)(Bp0 + k0);
    short8 b1 = *(const short8*)(const void*)(Bp1 + k0);
    __syncthreads();
    *(short8*)(AsB + wb0) = a0;
    *(short8*)(AsB + wb1) = a1;
    *(short8*)(BsB + wb0) = b0;
    *(short8*)(BsB + wb1) = b1;
    __syncthreads();
#pragma unroll
    for (int kk = 0; kk < 64; kk += 32) {
      const int kb = (kk + 8 * kgrp) * 2;
      short8 af0 = *(const short8*)(AsB + r0L * 128 + (kb ^ sw_r));
      short8 af1 = *(const short8*)(AsB + (r0L + 16) * 128 + (kb ^ sw_r));
      short8 bf0 = *(const short8*)(BsB + c0L * 128 + (kb ^ sw_c));
      short8 bf1 = *(const short8*)(BsB + (c0L + 16) * 128 + (kb ^ sw_c));
      acc00 = __builtin_amdgcn_mfma_f32_16x16x32_bf16(af0, bf0, acc00, 0, 0, 0);
      acc01 = __builtin_amdgcn_mfma_f32_16x16x32_bf16(af0, bf1, acc01, 0, 0, 0);
      acc10 = __builtin_amdgcn_mfma_f32_16x16x32_bf16(af1, bf0, acc10, 0, 0, 0);
      acc11 = __builtin_amdgcn_mfma_f32_16x16x32_bf16(af1, bf1, acc11, 0, 0, 0);
    }
  }
}

// small GEMM (fw = x@W): whole K, writes C f32 row-major + Ct bf16 [128, NROW]
__global__ __launch_bounds__(256) void gemm_small(float* __restrict__ C,
    unsigned short* __restrict__ Ct,
    const unsigned short* __restrict__ A, const unsigned short* __restrict__ Bt, int K)
{
  __shared__ __align__(16) unsigned short As[64 * 64];
  __shared__ __align__(16) unsigned short Bs[64 * 64];
  const int m0 = blockIdx.x * 64, n0 = blockIdx.y * 64;
  f32x4 acc00 = {}, acc01 = {}, acc10 = {}, acc11 = {};
  gemm_core(acc00, acc01, acc10, acc11, A, Bt, K, 0, K, m0, n0, As, Bs);

  const int lane = threadIdx.x & 63;
  const int w = threadIdx.x >> 6;
  const int orow = m0 + (w >> 1) * 32 + (lane >> 4) * 4;
  const int ocol = n0 + (w & 1) * 32 + (lane & 15);
#pragma unroll
  for (int reg = 0; reg < 4; ++reg) {
    C[(size_t)(orow + reg) * 128 + ocol]           = acc00[reg];
    C[(size_t)(orow + reg) * 128 + ocol + 16]      = acc01[reg];
    C[(size_t)(orow + 16 + reg) * 128 + ocol]      = acc10[reg];
    C[(size_t)(orow + 16 + reg) * 128 + ocol + 16] = acc11[reg];
  }
  ushort4 o;
  o.x = f2b(acc00[0]); o.y = f2b(acc00[1]); o.z = f2b(acc00[2]); o.w = f2b(acc00[3]);
  *(ushort4*)(Ct + (size_t)ocol * NROW + orow) = o;
  o.x = f2b(acc10[0]); o.y = f2b(acc10[1]); o.z = f2b(acc10[2]); o.w = f2b(acc10[3]);
  *(ushort4*)(Ct + (size_t)ocol * NROW + orow + 16) = o;
  o.x = f2b(acc01[0]); o.y = f2b(acc01[1]); o.z = f2b(acc01[2]); o.w = f2b(acc01[3]);
  *(ushort4*)(Ct + (size_t)(ocol + 16) * NROW + orow) = o;
  o.x = f2b(acc11[0]); o.y = f2b(acc11[1]); o.z = f2b(acc11[2]); o.w = f2b(acc11[3]);
  *(ushort4*)(Ct + (size_t)(ocol + 16) * NROW + orow + 16) = o;
}

// ================= split-K GEMM: BM=32 x BN=128, BK=64, grid (128,1,SPLIT)=1024 blocks ====
// global_load_lds dwordx4 staging, pre-swizzled global source, linear LDS dest,
// swizzled ds_read_b128. 4 waves 2x2: wave = 16 rows x 64 cols = 1x4 frags, bf16 partials.
__global__ __launch_bounds__(256) void gemm_sk(unsigned short* __restrict__ P,
    const unsigned short* __restrict__ A, const unsigned short* __restrict__ Bt,
    int K, int KS)
{
  __shared__ __align__(16) unsigned short As[32 * 64];    // 4 KB
  __shared__ __align__(16) unsigned short Bs[128 * 64];   // 16 KB
  const int tid = threadIdx.x;
  const int lane = tid & 63;
  const int w = tid >> 6;
  const int wr = w >> 1, wc = w & 1;
  const int m0 = blockIdx.x * 32;
  const int s = blockIdx.z;
  const int kbeg = s * KS, kend = kbeg + KS;

  const int lrow = lane >> 3;                       // 0..7
  const int osw = (((lane & 7) ^ lrow) << 4);       // pre-swizzled byte offset in 128B row
  const unsigned char* Ab = (const unsigned char*)A;
  const unsigned char* Bb = (const unsigned char*)Bt;
  const size_t a_src = (size_t)(m0 + w * 8 + lrow) * ((size_t)K * 2) + osw;
  size_t b_src[4];
#pragma unroll
  for (int j = 0; j < 4; ++j)                       // B rows: w*32 + j*8 + lrow (0..127)
    b_src[j] = (size_t)(w * 32 + j * 8 + lrow) * ((size_t)K * 2) + osw;

  char* AsB = (char*)As;
  char* BsB = (char*)Bs;

  f32x4 acc[4] = {};

  const int krow = lane & 15, kgrp = lane >> 4;
  const int rA = wr * 16 + krow;                    // (rA&7) == lane&7
  const int rB = wc * 64 + krow;                    // + nf*16 ; (rB&7) == lane&7
  const int swz = (lane & 7) << 4;
  const int kb_base = kgrp * 16;

  for (int k0 = kbeg; k0 < kend; k0 += 64) {
    __syncthreads();
    __builtin_amdgcn_global_load_lds(
        (const __attribute__((address_space(1))) void*)(Ab + a_src + (size_t)k0 * 2),
        (__attribute__((address_space(3))) void*)(AsB + w * 1024), 16, 0, 0);
#pragma unroll
    for (int j = 0; j < 4; ++j)
      __builtin_amdgcn_global_load_lds(
          (const __attribute__((address_space(1))) void*)(Bb + b_src[j] + (size_t)k0 * 2),
          (__attribute__((address_space(3))) void*)(BsB + (w * 4 + j) * 1024), 16, 0, 0);
    __syncthreads();
#pragma unroll
    for (int ks = 0; ks < 2; ++ks) {
      const int kb = ks * 64 + kb_base;
      short8 af = *(const short8*)(AsB + rA * 128 + (kb ^ swz));
      short8 bf0 = *(const short8*)(BsB + (rB) * 128 + (kb ^ swz));
      short8 bf1 = *(const short8*)(BsB + (rB + 16) * 128 + (kb ^ swz));
      short8 bf2 = *(const short8*)(BsB + (rB + 32) * 128 + (kb ^ swz));
      short8 bf3 = *(const short8*)(BsB + (rB + 48) * 128 + (kb ^ swz));
      acc[0] = __builtin_amdgcn_mfma_f32_16x16x32_bf16(af, bf0, acc[0], 0, 0, 0);
      acc[1] = __builtin_amdgcn_mfma_f32_16x16x32_bf16(af, bf1, acc[1], 0, 0, 0);
      acc[2] = __builtin_amdgcn_mfma_f32_16x16x32_bf16(af, bf2, acc[2], 0, 0, 0);
      acc[3] = __builtin_amdgcn_mfma_f32_16x16x32_bf16(af, bf3, acc[3], 0, 0, 0);
    }
  }

  unsigned short* C = P + (size_t)s * NM;
  const int orow = m0 + wr * 16 + kgrp * 4;         // C/D: col=lane&15, row=(lane>>4)*4+reg
  const int ocol = wc * 64 + krow;
#pragma unroll
  for (int nf = 0; nf < 4; ++nf)
#pragma unroll
    for (int reg = 0; reg < 4; ++reg)
      C[(size_t)(orow + reg) * 128 + ocol + nf * 16] = f2b(acc[nf][reg]);
}

// ================= reduce: sum SPLIT bf16 partials, optional combine, write f32 + bf16^T
// MODE 0: out = sum            MODE 1: out = d .* (p3*x1 + p4*x2 + p5*sum)
template<int MODE>
__global__ __launch_bounds__(256) void reduce_tr(float* __restrict__ outF,
    unsigned short* __restrict__ outT, const unsigned short* __restrict__ P,
    const float* __restrict__ x1, const float* __restrict__ x2,
    const float* __restrict__ dv, const float* __restrict__ par)
{
  __shared__ float sh[32][33];
  const int r0 = blockIdx.x * 32, c0 = blockIdx.y * 32;
  const int t = threadIdx.x;
  const int r = t >> 3, c4 = (t & 7) * 4;
  const size_t base = (size_t)(r0 + r) * 128 + c0 + c4;

  float4 acc = {0.f, 0.f, 0.f, 0.f};
#pragma unroll
  for (int s = 0; s < SPLIT; ++s) {
    ushort4 v = *(const ushort4*)(P + (size_t)s * NM + base);
    acc.x += b2f(v.x); acc.y += b2f(v.y); acc.z += b2f(v.z); acc.w += b2f(v.w);
  }
  if (MODE == 1) {
    float d_ = dv[r0 + r];
    float p3 = par[3], p4 = par[4], p5 = par[5];
    float4 a = *(const float4*)(x1 + base);
    float4 b = *(const float4*)(x2 + base);
    acc.x = d_ * (p3 * a.x + p4 * b.x + p5 * acc.x);
    acc.y = d_ * (p3 * a.y + p4 * b.y + p5 * acc.y);
    acc.z = d_ * (p3 * a.z + p4 * b.z + p5 * acc.z);
    acc.w = d_ * (p3 * a.w + p4 * b.w + p5 * acc.w);
  }
  *(float4*)(outF + base) = acc;
  sh[r][c4 + 0] = acc.x; sh[r][c4 + 1] = acc.y; sh[r][c4 + 2] = acc.z; sh[r][c4 + 3] = acc.w;
  __syncthreads();
  const int c = t >> 3, j4 = (t & 7) * 4;
  ushort4 o;
  o.x = f2b(sh[j4 + 0][c]); o.y = f2b(sh[j4 + 1][c]);
  o.z = f2b(sh[j4 + 2][c]); o.w = f2b(sh[j4 + 3][c]);
  *(ushort4*)(outT + (size_t)(c0 + c) * NROW + r0 + j4) = o;
}

// h1 = relu(p0*y + p1*q1 + p2*sum(P)) -> bf16 row-major
__global__ __launch_bounds__(256) void reduce_h1(unsigned short* __restrict__ ho,
    const unsigned short* __restrict__ P, const float* __restrict__ y,
    const float* __restrict__ q1, const float* __restrict__ par)
{
  size_t i = ((size_t)blockIdx.x * 256 + threadIdx.x) * 4;
  float4 acc = {0.f, 0.f, 0.f, 0.f};
#pragma unroll
  for (int s = 0; s < SPLIT; ++s) {
    ushort4 v = *(const ushort4*)(P + (size_t)s * NM + i);
    acc.x += b2f(v.x); acc.y += b2f(v.y); acc.z += b2f(v.z); acc.w += b2f(v.w);
  }
  float p0 = par[0], p1 = par[1], p2 = par[2];
  float4 a = *(const float4*)(y + i), b = *(const float4*)(q1 + i);
  ushort4 o;
  o.x = f2b(fmaxf(p0 * a.x + p1 * b.x + p2 * acc.x, 0.f));
  o.y = f2b(fmaxf(p0 * a.y + p1 * b.y + p2 * acc.y, 0.f));
  o.z = f2b(fmaxf(p0 * a.z + p1 * b.z + p2 * acc.z, 0.f));
  o.w = f2b(fmaxf(p0 * a.w + p1 * b.w + p2 * acc.w, 0.f));
  *(ushort4*)(ho + i) = o;
}

// out = (ps0+ps1) * log_softmax(p0*y + p1*q1 + p2*sum(P), rows of 128) -> f32
__global__ __launch_bounds__(256) void final_sum(float* __restrict__ out,
    const unsigned short* __restrict__ P, const float* __restrict__ y,
    const float* __restrict__ q1, const float* __restrict__ par,
    const float* __restrict__ ps)
{
  int row = blockIdx.x * 4 + (threadIdx.x >> 6);
  int lane = threadIdx.x & 63;
  size_t i0 = (size_t)row * 128 + lane;
  size_t i1 = i0 + 64;
  float s0 = 0.f, s1 = 0.f;
#pragma unroll
  for (int s = 0; s < SPLIT; ++s) {
    s0 += b2f(P[(size_t)s * NM + i0]);
    s1 += b2f(P[(size_t)s * NM + i1]);
  }
  float p0 = par[0], p1 = par[1], p2 = par[2];
  float a0 = p0 * y[i0] + p1 * q1[i0] + p2 * s0;
  float a1 = p0 * y[i1] + p1 * q1[i1] + p2 * s1;
  float m = fmaxf(a0, a1);
#pragma unroll
  for (int off = 32; off; off >>= 1) m = fmaxf(m, __shfl_xor(m, off));
  float s = expf(a0 - m) + expf(a1 - m);
#pragma unroll
  for (int off = 32; off; off >>= 1) s += __shfl_xor(s, off);
  float ls = m + logf(s);
  float c = ps[0] + ps[1];
  out[i0] = c * (a0 - ls);
  out[i1] = c * (a1 - ls);
}

extern "C" void kernel_launch(void* const* d_in, const int* in_sizes, int n_in,
                              void* d_out, int out_size, void* d_ws, size_t ws_size,
                              hipStream_t stream) {
  (void)in_sizes; (void)n_in; (void)out_size; (void)ws_size;
  const float* features = (const float*)d_in[0];
  const float* Theta    = (const float*)d_in[1];
  const float* W1       = (const float*)d_in[2];
  const float* d1       = (const float*)d_in[3];
  const float* par1     = (const float*)d_in[4];
  const float* W2       = (const float*)d_in[5];
  const float* d2       = (const float*)d_in[6];
  const float* par2     = (const float*)d_in[7];
  const float* psnap    = (const float*)d_in[8];
  float* out            = (float*)d_out;

  char* w = (char*)d_ws;
  unsigned short* Thb  = (unsigned short*)w;  w += (size_t)4096 * 4096 * 2;
  unsigned short* Ttb  = (unsigned short*)w;  w += (size_t)4096 * 4096 * 2;
  unsigned short* fb   = (unsigned short*)w;  w += (size_t)4096 * 512 * 2;
  unsigned short* W1bt = (unsigned short*)w;  w += (size_t)128 * 512 * 2;
  unsigned short* W2bt = (unsigned short*)w;  w += (size_t)128 * 128 * 2;
  unsigned short* fwbt = (unsigned short*)w;  w += (size_t)128 * 4096 * 2;
  unsigned short* t1bt = (unsigned short*)w;  w += (size_t)128 * 4096 * 2;
  unsigned short* ybt  = (unsigned short*)w;  w += (size_t)128 * 4096 * 2;
  unsigned short* p1bt = (unsigned short*)w;  w += (size_t)128 * 4096 * 2;
  unsigned short* h1b  = (unsigned short*)w;  w += (size_t)4096 * 128 * 2;
  float* fwf = (float*)w;                     w += (size_t)4096 * 128 * 4;
  float* t1f = (float*)w;                     w += (size_t)4096 * 128 * 4;
  float* yf  = (float*)w;                     w += (size_t)4096 * 128 * 4;
  float* p1f = (float*)w;                     w += (size_t)4096 * 128 * 4;
  unsigned short* Pp = (unsigned short*)w;    w += (size_t)SPLIT * 4096 * 128 * 2;

  // prep
  prep_theta<<<dim3(64, 64), 256, 0, stream>>>(Thb, Ttb, Theta);
  cvt_bf16<<<2048, 256, 0, stream>>>(fb, features);
  transpose_cvt<<<dim3(16, 4), 256, 0, stream>>>(W1bt, W1, 512);
  transpose_cvt<<<dim3(4, 4), 256, 0, stream>>>(W2bt, W2, 128);

  const dim3 gg(64, 2);            // small GEMM grid
  const dim3 gk(128, 1, SPLIT);    // split-K GEMM grid (1024 blocks, BM=32 full-width)
  const dim3 rg(128, 4);           // reduce_tr grid

  // ---- layer 1
  gemm_small<<<gg, 256, 0, stream>>>(fwf, fwbt, fb, W1bt, 512);
  gemm_sk<<<gk, 256, 0, stream>>>(Pp, Ttb, fwbt, 4096, 512);
  reduce_tr<0><<<rg, 256, 0, stream>>>(t1f, t1bt, Pp, nullptr, nullptr, nullptr, nullptr);
  gemm_sk<<<gk, 256, 0, stream>>>(Pp, Ttb, t1bt, 4096, 512);
  reduce_tr<1><<<rg, 256, 0, stream>>>(yf, ybt, Pp, fwf, t1f, d1, par1);
  gemm_sk<<<gk, 256, 0, stream>>>(Pp, Thb, ybt, 4096, 512);
  reduce_tr<0><<<rg, 256, 0, stream>>>(p1f, p1bt, Pp, nullptr, nullptr, nullptr, nullptr);
  gemm_sk<<<gk, 256, 0, stream>>>(Pp, Thb, p1bt, 4096, 512);
  reduce_h1<<<512, 256, 0, stream>>>(h1b, Pp, yf, p1f, par1);

  // ---- layer 2
  gemm_small<<<gg, 256, 0, stream>>>(fwf, fwbt, h1b, W2bt, 128);
  gemm_sk<<<gk, 256, 0, stream>>>(Pp, Ttb, fwbt, 4096, 512);
  reduce_tr<0><<<rg, 256, 0, stream>>>(t1f, t1bt, Pp, nullptr, nullptr, nullptr, nullptr);
  gemm_sk<<<gk, 256, 0, stream>>>(Pp, Ttb, t1bt, 4096, 512);
  reduce_tr<1><<<rg, 256, 0, stream>>>(yf, ybt, Pp, fwf, t1f, d2, par2);
  gemm_sk<<<gk, 256, 0, stream>>>(Pp, Thb, ybt, 4096, 512);
  reduce_tr<0><<<rg, 256, 0, stream>>>(p1f, p1bt, Pp, nullptr, nullptr, nullptr, nullptr);
  gemm_sk<<<gk, 256, 0, stream>>>(Pp, Thb, p1bt, 4096, 512);
  final_sum<<<1024, 256, 0, stream>>>(out, Pp, yf, p1f, par2, psnap);
}